// Round 14
// baseline (55.663 us; speedup 1.0000x reference)
//
#include <hip/hip_runtime.h>
#include <hip/hip_bf16.h>

#define VN 3129
#define DN 768
#define BN 2048
#define NT 3200              // VN padded (multiple of 64 and 128)
#define NB64 50              // 64-wide tile blocks per side
#define NTRI64 1275          // 50*51/2
#define NBLK_LOGEXP 512
#define NBLK_COMPACT 512
#define GRID_MEGA (NTRI64 + NBLK_LOGEXP + NBLK_COMPACT)   // 2299

typedef __attribute__((ext_vector_type(8))) short bf16x8;
typedef __attribute__((ext_vector_type(4))) float f32x4;

typedef __attribute__((address_space(3))) void as3_void;
typedef __attribute__((address_space(1))) const void as1_cvoid;

__device__ __forceinline__ void gload16(const void* g, void* l) {
    __builtin_amdgcn_global_load_lds((as1_cvoid*)g, (as3_void*)l, 16, 0, 0);
}

__device__ __forceinline__ unsigned sortable_f32(float f) {
    unsigned u = __float_as_uint(f);
    return (u & 0x80000000u) ? ~u : (u | 0x80000000u);
}

// non-temporal float4 load (sets nt bit -> streaming lines don't evict L2 working set)
__device__ __forceinline__ f32x4 nt_load4(const float* p) {
    return __builtin_nontemporal_load((const f32x4*)p);
}

// bijective XCD swizzle over the gram/amax range 0..1274 (m204 formula)
__device__ __forceinline__ int xcd_swz(int orig) {
    const int q = NTRI64 / 8, r = NTRI64 % 8;   // 159, 3
    int xcd = orig & 7, idx = orig >> 3;
    return (xcd < r ? xcd * (q + 1) : r * (q + 1) + (xcd - r) * q) + idx;
}

// ---------------- fast path ws layout (bytes) ----------------
static const size_t WB_EB  = 0;          // bf16 E padded to NT rows (4,915,200)
static const size_t WB_SIM = 4915200;    // bf16 sim tiles 1275 x 4096 (10,444,800)
static const size_t WB_N2  = 15360000;   // float[3200]
static const size_t WB_ARG = 15372800;   // u32[3200] packed (score20 | j12)
static const size_t WB_P1  = 15385600;   // float[2048] logexp partials (use 512)
static const size_t WB_P2  = 15393792;   // float[2048] scatter partials
static const size_t WB_GSL = 15401984;   // u32 [2048][64]
static const size_t WB_LSL = 15926272;   // f32 [2048][64]
static const size_t WB_CNT = 16450560;   // u32 [2048]
static const size_t WS_NEEDED = 16458752;

// ---------------- kernel A: zero + E->bf16 ----------------
__global__ __launch_bounds__(256) void k_prep2(const float* __restrict__ E,
                                               unsigned short* __restrict__ Eb,
                                               unsigned* __restrict__ zwords) {
    const int gid = blockIdx.x * 256 + threadIdx.x;
    const int gstride = gridDim.x * 256;

    for (int i = gid; i < 6400; i += gstride) zwords[i] = 0u;

    const int nchunks = NT * DN / 8;              // 307200
    for (int chunk = gid; chunk < nchunks; chunk += gstride) {
        int row = chunk / (DN / 8);
        int cc = (chunk % (DN / 8)) * 8;
        unsigned short o[8];
        if (row < VN) {
            const float* src = E + (size_t)row * DN + cc;
            float4 a = *(const float4*)src;
            float4 b = *(const float4*)(src + 4);
            float v[8] = {a.x, a.y, a.z, a.w, b.x, b.y, b.z, b.w};
#pragma unroll
            for (int t = 0; t < 8; ++t) {
                unsigned u = __float_as_uint(v[t]);
                u += 0x7FFFu + ((u >> 16) & 1u);      // RNE
                o[t] = (unsigned short)(u >> 16);
            }
        } else {
#pragma unroll
            for (int t = 0; t < 8; ++t) o[t] = 0;
        }
        *(uint4*)(Eb + (size_t)chunk * 8) = *(const uint4*)o;
    }
}

// ---------------- mega: gram | NT-logexp | NT-label-compaction ----------------
__global__ __launch_bounds__(256) void k_mega(const unsigned short* __restrict__ Eb,
                                              const float* __restrict__ pred,
                                              const float* __restrict__ label,
                                              float* __restrict__ n2,
                                              unsigned short* __restrict__ simT,
                                              float* __restrict__ part1,
                                              unsigned* __restrict__ gsl,
                                              float* __restrict__ lsl,
                                              unsigned* __restrict__ cntarr) {
    const int bid = blockIdx.x;
    const int tid = threadIdx.x;
    const int lane = tid & 63;
    const int w = tid >> 6;

    if (bid < NTRI64) {
        // ================= role A: 64x64 Gram tile (verified R9 body) =================
        __shared__ __align__(16) unsigned short As[64 * 64];
        __shared__ __align__(16) unsigned short Bs[64 * 64];
        const int wr = w >> 1, wc = w & 1;

        int t = xcd_swz(bid), bi = 0, rem = t;
        while (rem >= NB64 - bi) { rem -= NB64 - bi; ++bi; }
        const int bj = bi + rem;
        const int i0 = bi * 64, j0 = bj * 64;

        const int srow = lane >> 3;
        const int scol = 8 * ((lane & 7) ^ (lane >> 3));   // inverse-swizzled source col

        f32x4 acc[2][2] = {};

        for (int k0 = 0; k0 < DN; k0 += 64) {
#pragma unroll
            for (int q = 0; q < 2; ++q) {
                int ci = w * 2 + q;
                int row = ci * 8 + srow;
                gload16(Eb + (size_t)(i0 + row) * DN + k0 + scol, As + ci * 512);
                gload16(Eb + (size_t)(j0 + row) * DN + k0 + scol, Bs + ci * 512);
            }
            __syncthreads();
            const int rA = wr * 32 + (lane & 15);
            const int rB = wc * 32 + (lane & 15);
            const int swr = (lane & 7) << 4;
            const int kb = (lane >> 4) * 16;
#pragma unroll
            for (int ks = 0; ks < 2; ++ks) {
                const int cb = (kb + ks * 64) ^ swr;
                bf16x8 af[2], bfr[2];
#pragma unroll
                for (int m = 0; m < 2; ++m)
                    af[m] = *(const bf16x8*)((const char*)As + (rA + m * 16) * 128 + cb);
#pragma unroll
                for (int n = 0; n < 2; ++n)
                    bfr[n] = *(const bf16x8*)((const char*)Bs + (rB + n * 16) * 128 + cb);
#pragma unroll
                for (int m = 0; m < 2; ++m)
#pragma unroll
                    for (int n = 0; n < 2; ++n)
                        acc[m][n] = __builtin_amdgcn_mfma_f32_16x16x32_bf16(
                            af[m], bfr[n], acc[m][n], 0, 0, 0);
            }
            __syncthreads();
        }

        // C/D layout: col = lane&15, row = (lane>>4)*4 + reg
        const int rr4 = (lane >> 4) * 4;

        // ---- sim tile store, lane-packed bf16: simT[t][tid][16] ----
        {
            unsigned op[8];
#pragma unroll
            for (int m = 0; m < 2; ++m)
#pragma unroll
                for (int n = 0; n < 2; ++n)
#pragma unroll
                    for (int ih = 0; ih < 2; ++ih) {
                        unsigned lo = __float_as_uint(acc[m][n][ih * 2]);
                        lo += 0x7FFFu + ((lo >> 16) & 1u);
                        unsigned hi = __float_as_uint(acc[m][n][ih * 2 + 1]);
                        hi += 0x7FFFu + ((hi >> 16) & 1u);
                        op[(m * 2 + n) * 2 + ih] = (lo >> 16) | (hi & 0xFFFF0000u);
                    }
            uint4* dst = (uint4*)(simT + (size_t)t * 4096 + (size_t)tid * 16);
            dst[0] = *(uint4*)&op[0];
            dst[1] = *(uint4*)&op[4];
        }

        // ---- n2 row sums ----
        __shared__ float red[64];
        if (tid < 64) red[tid] = 0.f;
        __syncthreads();
#pragma unroll
        for (int m = 0; m < 2; ++m)
#pragma unroll
            for (int i = 0; i < 4; ++i) {
                float s = acc[m][0][i] * acc[m][0][i] + acc[m][1][i] * acc[m][1][i];
                s += __shfl_xor(s, 1); s += __shfl_xor(s, 2);
                s += __shfl_xor(s, 4); s += __shfl_xor(s, 8);
                if ((lane & 15) == 0)
                    atomicAdd(&red[wr * 32 + m * 16 + rr4 + i], s);
            }
        __syncthreads();
        if (tid < 64) atomicAdd(&n2[i0 + tid], red[tid]);
        // ---- n2 col sums (off-diagonal only) ----
        if (bi != bj) {
            __syncthreads();
            if (tid < 64) red[tid] = 0.f;
            __syncthreads();
#pragma unroll
            for (int n = 0; n < 2; ++n) {
                float s = 0.f;
#pragma unroll
                for (int m = 0; m < 2; ++m)
#pragma unroll
                    for (int i = 0; i < 4; ++i) { float x = acc[m][n][i]; s += x * x; }
                s += __shfl_xor(s, 16); s += __shfl_xor(s, 32);
                if (lane < 16)
                    atomicAdd(&red[wc * 32 + n * 16 + lane], s);
            }
            __syncthreads();
            if (tid < 64) atomicAdd(&n2[j0 + tid], red[tid]);
        }
    } else if (bid < NTRI64 + NBLK_LOGEXP) {
        // ================= role B: pred logexp stream (non-temporal) =================
        const int rb = bid - NTRI64;             // 0..511
        const int n4 = BN * VN / 4;              // 1,602,048
        float acc = 0.f;
        for (int i = rb * 256 + tid; i < n4; i += NBLK_LOGEXP * 256) {
            f32x4 v = nt_load4(pred + (size_t)i * 4);
            acc += fmaxf(v[0], 0.f) + __logf(1.f + __expf(-fabsf(v[0])));
            acc += fmaxf(v[1], 0.f) + __logf(1.f + __expf(-fabsf(v[1])));
            acc += fmaxf(v[2], 0.f) + __logf(1.f + __expf(-fabsf(v[2])));
            acc += fmaxf(v[3], 0.f) + __logf(1.f + __expf(-fabsf(v[3])));
        }
        for (int off = 32; off; off >>= 1) acc += __shfl_down(acc, off);
        __shared__ float wsum[4];
        if (lane == 0) wsum[w] = acc;
        __syncthreads();
        if (tid == 0) part1[rb] = wsum[0] + wsum[1] + wsum[2] + wsum[3];
    } else {
        // ================= role C: label compaction (non-temporal loads) =================
        const int row = (bid - NTRI64 - NBLK_LOGEXP) * 4 + w;   // 0..2047
        if (row < BN) {
            const float* lrow = label + (size_t)row * VN;
            f32x4 buf[12];
#pragma unroll
            for (int c = 0; c < 12; ++c)
                buf[c] = nt_load4(lrow + c * 256 + lane * 4);
            float tailv = 0.f;
            const int gtail = 3072 + lane;
            if (lane < VN - 3072) tailv = __builtin_nontemporal_load(lrow + gtail);

            int base = 0;
#pragma unroll
            for (int c = 0; c < 12; ++c) {
#pragma unroll
                for (int e = 0; e < 4; ++e) {
                    float l = buf[c][e];
                    unsigned long long mask = __ballot(l != 0.f);
                    if (l != 0.f) {
                        int pos = base + __popcll(mask & ((1ull << lane) - 1ull));
                        if (pos < 64) {
                            gsl[row * 64 + pos] = (unsigned)(c * 256 + lane * 4 + e);
                            lsl[row * 64 + pos] = l;
                        }
                    }
                    base += __popcll(mask);
                }
            }
            {
                unsigned long long mask = __ballot(tailv != 0.f);
                if (tailv != 0.f) {
                    int pos = base + __popcll(mask & ((1ull << lane) - 1ull));
                    if (pos < 64) {
                        gsl[row * 64 + pos] = (unsigned)gtail;
                        lsl[row * 64 + pos] = tailv;
                    }
                }
                base += __popcll(mask);
            }
            if (lane == 0) cntarr[row] = (unsigned)base;
        }
    }
}

// ---------------- argmax over stored sim tiles (u32 keys, mul-only) ----------------
__global__ __launch_bounds__(256) void k_amax64(const unsigned short* __restrict__ simT,
                                                const float* __restrict__ n2,
                                                unsigned* __restrict__ argbest) {
    const int tid = threadIdx.x, lane = tid & 63, w = tid >> 6;
    const int wr = w >> 1, wc = w & 1;
    int t = xcd_swz(blockIdx.x), bi = 0, rem = t;
    while (rem >= NB64 - bi) { rem -= NB64 - bi; ++bi; }
    const int bj = bi + rem;
    const int i0 = bi * 64, j0 = bj * 64;

    __shared__ float rni_s[64], rnj_s[64];
    __shared__ unsigned rbest[64], cbest[64];
    if (tid < 64) {
        rni_s[tid] = rsqrtf(n2[i0 + tid]);
        rnj_s[tid] = rsqrtf(n2[j0 + tid]);
        rbest[tid] = 0u; cbest[tid] = 0u;
    }
    __syncthreads();

    const uint4* src = (const uint4*)(simT + (size_t)t * 4096 + (size_t)tid * 16);
    uint4 iv0 = src[0], iv1 = src[1];
    unsigned ip[8];
    *(uint4*)&ip[0] = iv0; *(uint4*)&ip[4] = iv1;

    const int rr4 = (lane >> 4) * 4;
    int rg[8]; float rni8[8];
#pragma unroll
    for (int m = 0; m < 2; ++m)
#pragma unroll
        for (int i = 0; i < 4; ++i) {
            int rl = wr * 32 + m * 16 + rr4 + i;
            rg[m * 4 + i] = i0 + rl;
            rni8[m * 4 + i] = rni_s[rl];
        }
    int cg2[2]; float rnj2[2];
#pragma unroll
    for (int n = 0; n < 2; ++n) {
        int cl = wc * 32 + n * 16 + (lane & 15);
        cg2[n] = j0 + cl;
        rnj2[n] = rnj_s[cl];
    }

    // row side
#pragma unroll
    for (int m = 0; m < 2; ++m)
#pragma unroll
        for (int i = 0; i < 4; ++i) {
            int ig = rg[m * 4 + i];
            unsigned best = 0u;
#pragma unroll
            for (int n = 0; n < 2; ++n) {
                int jg = cg2[n];
                if (jg < VN && jg != ig) {
                    unsigned wv = ip[(m * 2 + n) * 2 + (i >> 1)];
                    float v = __uint_as_float((i & 1) ? (wv & 0xFFFF0000u) : (wv << 16));
                    unsigned key = (sortable_f32(v * rnj2[n]) & 0xFFFFF000u) | (unsigned)jg;
                    best = max(best, key);
                }
            }
            best = max(best, __shfl_xor(best, 1));
            best = max(best, __shfl_xor(best, 2));
            best = max(best, __shfl_xor(best, 4));
            best = max(best, __shfl_xor(best, 8));
            if ((lane & 15) == 0)
                atomicMax(&rbest[wr * 32 + m * 16 + rr4 + i], best);
        }

    // col side (symmetry)
    if (bi != bj) {
#pragma unroll
        for (int n = 0; n < 2; ++n) {
            unsigned best = 0u;
#pragma unroll
            for (int m = 0; m < 2; ++m)
#pragma unroll
                for (int i = 0; i < 4; ++i) {
                    int ig = rg[m * 4 + i];
                    if (ig < VN) {
                        unsigned wv = ip[(m * 2 + n) * 2 + (i >> 1)];
                        float v = __uint_as_float((i & 1) ? (wv & 0xFFFF0000u) : (wv << 16));
                        unsigned key = (sortable_f32(v * rni8[m * 4 + i]) & 0xFFFFF000u)
                                       | (unsigned)ig;
                        best = max(best, key);
                    }
                }
            best = max(best, __shfl_xor(best, 16));
            best = max(best, __shfl_xor(best, 32));
            if (lane < 16)
                atomicMax(&cbest[wc * 32 + n * 16 + lane], best);
        }
    }
    __syncthreads();
    if (tid < 64) {
        unsigned rb = rbest[tid];
        if (rb) atomicMax(&argbest[i0 + tid], rb);
        if (bi != bj) {
            unsigned cb = cbest[tid];
            if (cb) atomicMax(&argbest[j0 + tid], cb);
        }
    }
}

// ---------------- scatter from compacted lists (one wave per row) ----------------
__global__ __launch_bounds__(64) void k_scatter(const float* __restrict__ pred,
                                                const float* __restrict__ label,
                                                const unsigned* __restrict__ argbest,
                                                const unsigned* __restrict__ gsl,
                                                const float* __restrict__ lsl,
                                                const unsigned* __restrict__ cntarr,
                                                float* __restrict__ part2) {
    const int i = blockIdx.x;
    const int lane = threadIdx.x;
    const int cnt = (int)cntarr[i];
    float contrib = 0.f;

    if (cnt <= 64) {
        unsigned g = 0, tgt = 0xFFFFFFFFu;
        float l = 0.f;
        if (lane < cnt) {
            g = gsl[i * 64 + lane];
            l = lsl[i * 64 + lane];
            tgt = argbest[g] & 0xFFFu;
        }
        __shared__ unsigned tg_s[64], g_s[64];
        tg_s[lane] = tgt; g_s[lane] = g;
        __syncthreads();
        if (lane < cnt) {
            bool keep = true;
            for (int o = 0; o < cnt; ++o)
                if (tg_s[o] == tgt && g_s[o] > g) { keep = false; break; }
            if (keep) contrib = pred[(size_t)i * VN + tgt] * l;
        }
    } else {
        // exact fallback: rescan raw label row
        __shared__ int c2;
        __shared__ unsigned short gs2[256], ts2[256];
        __shared__ float ls2[256];
        if (lane == 0) c2 = 0;
        __syncthreads();
        const float* lrow = label + (size_t)i * VN;
        for (int g = lane; g < VN; g += 64) {
            float l = lrow[g];
            if (l != 0.f) {
                int p = atomicAdd(&c2, 1);
                if (p < 256) {
                    gs2[p] = (unsigned short)g;
                    ls2[p] = l;
                    ts2[p] = (unsigned short)(argbest[g] & 0xFFFu);
                }
            }
        }
        __syncthreads();
        int m = min(c2, 256);
        for (int e = lane; e < m; e += 64) {
            bool keep = true;
            for (int o = 0; o < m; ++o)
                if (ts2[o] == ts2[e] && gs2[o] > gs2[e]) keep = false;
            if (keep) contrib += pred[(size_t)i * VN + ts2[e]] * ls2[e];
        }
    }

    for (int off = 32; off; off >>= 1) contrib += __shfl_down(contrib, off);
    if (lane == 0) part2[i] = contrib;
}

__global__ __launch_bounds__(256) void k_final(const float* __restrict__ part1, int p1n,
                                               const float* __restrict__ part2,
                                               float* __restrict__ out) {
    int tid = threadIdx.x;
    double acc = 0.0;
    for (int i = tid; i < p1n; i += 256) acc += (double)part1[i];
    for (int i = tid; i < BN; i += 256) acc -= (double)part2[i];
    __shared__ double red[256];
    red[tid] = acc;
    __syncthreads();
    for (int s = 128; s; s >>= 1) {
        if (tid < s) red[tid] += red[tid + s];
        __syncthreads();
    }
    if (tid == 0) out[0] = (float)(red[0] / (double)BN);
}

// ---------------- fallback path (small ws): fp32 Gram + scan scatter ----------------
__global__ __launch_bounds__(256) void k_zero(unsigned int* p, int nwords) {
    int idx = blockIdx.x * 256 + threadIdx.x;
    for (int i = idx; i < nwords; i += gridDim.x * 256) p[i] = 0u;
}

__global__ __launch_bounds__(256) void k_logexp(const float* __restrict__ pred,
                                                float* __restrict__ part1) {
    int tid = threadIdx.x;
    const float4* p4 = (const float4*)pred;
    const int n4 = BN * VN / 4;
    float acc = 0.f;
    for (int i = blockIdx.x * 256 + tid; i < n4; i += gridDim.x * 256) {
        float4 v = p4[i];
        acc += fmaxf(v.x, 0.f) + log1pf(__expf(-fabsf(v.x)));
        acc += fmaxf(v.y, 0.f) + log1pf(__expf(-fabsf(v.y)));
        acc += fmaxf(v.z, 0.f) + log1pf(__expf(-fabsf(v.z)));
        acc += fmaxf(v.w, 0.f) + log1pf(__expf(-fabsf(v.w)));
    }
    for (int off = 32; off; off >>= 1) acc += __shfl_down(acc, off);
    __shared__ float wsum[4];
    int lane = tid & 63, wid = tid >> 6;
    if (lane == 0) wsum[wid] = acc;
    __syncthreads();
    if (tid == 0) part1[blockIdx.x] = wsum[0] + wsum[1] + wsum[2] + wsum[3];
}

template <int PASS>
__global__ __launch_bounds__(256) void k_gemm(const float* __restrict__ E,
                                              float* __restrict__ n2,
                                              unsigned* __restrict__ argbest) {
    __shared__ float As[16][132];
    __shared__ float Bs[16][132];
    const int tid = threadIdx.x;
    const int tx = tid & 15, ty = tid >> 4;
    const int i0 = blockIdx.y * 128, j0 = blockIdx.x * 128;
    float acc[8][8] = {};

    for (int k0 = 0; k0 < DN; k0 += 16) {
#pragma unroll
        for (int h = 0; h < 2; ++h) {
            int f = tid + h * 256;
            int r = f >> 2;
            int kq = (f & 3) << 2;
            int gi = i0 + r;
            float4 va = make_float4(0.f, 0.f, 0.f, 0.f);
            if (gi < VN) va = *(const float4*)(E + gi * DN + k0 + kq);
            As[kq + 0][r] = va.x; As[kq + 1][r] = va.y;
            As[kq + 2][r] = va.z; As[kq + 3][r] = va.w;
            int gj = j0 + r;
            float4 vb = make_float4(0.f, 0.f, 0.f, 0.f);
            if (gj < VN) vb = *(const float4*)(E + gj * DN + k0 + kq);
            Bs[kq + 0][r] = vb.x; Bs[kq + 1][r] = vb.y;
            Bs[kq + 2][r] = vb.z; Bs[kq + 3][r] = vb.w;
        }
        __syncthreads();
#pragma unroll
        for (int k = 0; k < 16; ++k) {
            float a[8], b[8];
            *(float4*)&a[0] = *(const float4*)&As[k][ty * 8];
            *(float4*)&a[4] = *(const float4*)&As[k][ty * 8 + 4];
            *(float4*)&b[0] = *(const float4*)&Bs[k][tx * 8];
            *(float4*)&b[4] = *(const float4*)&Bs[k][tx * 8 + 4];
#pragma unroll
            for (int m = 0; m < 8; ++m)
#pragma unroll
                for (int n = 0; n < 8; ++n)
                    acc[m][n] = fmaf(a[m], b[n], acc[m][n]);
        }
        __syncthreads();
    }

    if (PASS == 0) {
        __shared__ float nrow[128];
        if (tid < 128) nrow[tid] = 0.f;
        __syncthreads();
#pragma unroll
        for (int m = 0; m < 8; ++m) {
            float s = 0.f;
#pragma unroll
            for (int n = 0; n < 8; ++n) s += acc[m][n] * acc[m][n];
            atomicAdd(&nrow[ty * 8 + m], s);
        }
        __syncthreads();
        if (tid < 128 && i0 + tid < VN) atomicAdd(&n2[i0 + tid], nrow[tid]);
    } else {
        __shared__ unsigned brow[128];
        if (tid < 128) brow[tid] = 0u;
        __syncthreads();
        float rnj[8];
#pragma unroll
        for (int n = 0; n < 8; ++n) {
            int j = j0 + tx * 8 + n;
            rnj[n] = (j < VN) ? rsqrtf(n2[j]) : 0.f;
        }
#pragma unroll
        for (int m = 0; m < 8; ++m) {
            int i = i0 + ty * 8 + m;
            unsigned best = 0u;
#pragma unroll
            for (int n = 0; n < 8; ++n) {
                int j = j0 + tx * 8 + n;
                if (j < VN && j != i) {
                    unsigned key = (sortable_f32(acc[m][n] * rnj[n]) & 0xFFFFF000u) | (unsigned)j;
                    best = max(best, key);
                }
            }
            atomicMax(&brow[ty * 8 + m], best);
        }
        __syncthreads();
        if (tid < 128 && i0 + tid < VN) atomicMax(&argbest[i0 + tid], brow[tid]);
    }
}

__global__ __launch_bounds__(256) void k_scatter_scan(const float* __restrict__ pred,
                                                      const float* __restrict__ label,
                                                      const unsigned* __restrict__ argbest,
                                                      float* __restrict__ part2) {
    int i = blockIdx.x;
    int tid = threadIdx.x;
    __shared__ int cnt;
    __shared__ unsigned short gs[256];
    __shared__ unsigned short ts[256];
    __shared__ float ls[256];
    if (tid == 0) cnt = 0;
    __syncthreads();
    const float* lrow = label + (size_t)i * VN;
    for (int g = tid; g < VN; g += 256) {
        float l = lrow[g];
        if (l != 0.f) {
            int p = atomicAdd(&cnt, 1);
            if (p < 256) {
                gs[p] = (unsigned short)g;
                ls[p] = l;
                ts[p] = (unsigned short)(argbest[g] & 0xFFFu);
            }
        }
    }
    __syncthreads();
    int m = min(cnt, 256);
    float contrib = 0.f;
    for (int e = tid; e < m; e += 256) {
        bool keep = true;
        for (int o = 0; o < m; ++o)
            if (ts[o] == ts[e] && gs[o] > gs[e]) keep = false;
        if (keep) contrib += pred[(size_t)i * VN + ts[e]] * ls[e];
    }
    for (int off = 32; off; off >>= 1) contrib += __shfl_down(contrib, off);
    __shared__ float wsum[4];
    int lane = tid & 63, wid = tid >> 6;
    if (lane == 0) wsum[wid] = contrib;
    __syncthreads();
    if (tid == 0) part2[i] = wsum[0] + wsum[1] + wsum[2] + wsum[3];
}

extern "C" void kernel_launch(void* const* d_in, const int* in_sizes, int n_in,
                              void* d_out, int out_size, void* d_ws, size_t ws_size,
                              hipStream_t stream) {
    (void)in_sizes; (void)n_in; (void)out_size;
    const float* pred  = (const float*)d_in[0];
    const float* label = (const float*)d_in[1];
    const float* E     = (const float*)d_in[2];
    float* out = (float*)d_out;
    char* wsb = (char*)d_ws;

    if (ws_size >= WS_NEEDED) {
        unsigned short* Eb   = (unsigned short*)(wsb + WB_EB);
        unsigned short* simT = (unsigned short*)(wsb + WB_SIM);
        float* n2    = (float*)(wsb + WB_N2);
        unsigned* argbest = (unsigned*)(wsb + WB_ARG);
        float* part1 = (float*)(wsb + WB_P1);
        float* part2 = (float*)(wsb + WB_P2);
        unsigned* gsl = (unsigned*)(wsb + WB_GSL);
        float* lsl   = (float*)(wsb + WB_LSL);
        unsigned* cntarr = (unsigned*)(wsb + WB_CNT);

        k_prep2<<<1024, 256, 0, stream>>>(E, Eb, (unsigned*)n2);
        k_mega<<<GRID_MEGA, 256, 0, stream>>>(Eb, pred, label, n2, simT,
                                              part1, gsl, lsl, cntarr);
        k_amax64<<<NTRI64, 256, 0, stream>>>(simT, n2, argbest);
        k_scatter<<<BN, 64, 0, stream>>>(pred, label, argbest, gsl, lsl, cntarr, part2);
        k_final<<<1, 256, 0, stream>>>(part1, NBLK_LOGEXP, part2, out);
    } else {
        // minimal-ws fallback: fp32 Gram path
        float* ws = (float*)d_ws;
        float* n2    = ws;
        unsigned* argbest = (unsigned*)(ws + 3200);
        float* part1 = ws + 6400;
        float* part2 = ws + 8448;
        k_zero<<<10, 256, 0, stream>>>((unsigned int*)ws, 6400);
        k_logexp<<<2048, 256, 0, stream>>>(pred, part1);
        dim3 g((VN + 127) / 128, (VN + 127) / 128);
        k_gemm<0><<<g, 256, 0, stream>>>(E, n2, argbest);
        k_gemm<1><<<g, 256, 0, stream>>>(E, n2, argbest);
        k_scatter_scan<<<BN, 256, 0, stream>>>(pred, label, argbest, part2);
        k_final<<<1, 256, 0, stream>>>(part1, 2048, part2, out);
    }
}

// Round 15
// 54.082 us; speedup vs baseline: 1.0292x; 1.0292x over previous
//
#include <hip/hip_runtime.h>
#include <hip/hip_bf16.h>
#include <hip/hip_fp8.h>

#define VN 3129
#define DN 768
#define BN 2048
#define NT 3200              // VN padded (multiple of 64 and 128)
#define NB64 50              // 64-wide tile blocks per side
#define NTRI64 1275          // 50*51/2
#define NBLK_LOGEXP 512
#define NBLK_COMPACT 512
#define GRID_MEGA2 (NTRI64 + NBLK_LOGEXP + NBLK_COMPACT)   // 2299

typedef __attribute__((ext_vector_type(8))) short bf16x8;
typedef __attribute__((ext_vector_type(4))) float f32x4;

typedef __attribute__((address_space(3))) void as3_void;
typedef __attribute__((address_space(1))) const void as1_cvoid;

__device__ __forceinline__ void gload16(const void* g, void* l) {
    __builtin_amdgcn_global_load_lds((as1_cvoid*)g, (as3_void*)l, 16, 0, 0);
}

__device__ __forceinline__ unsigned sortable_f32(float f) {
    unsigned u = __float_as_uint(f);
    return (u & 0x80000000u) ? ~u : (u | 0x80000000u);
}

// bijective XCD swizzle over the gram/amax range 0..1274 (m204 formula)
__device__ __forceinline__ int xcd_swz(int orig) {
    const int q = NTRI64 / 8, r = NTRI64 % 8;   // 159, 3
    int xcd = orig & 7, idx = orig >> 3;
    return (xcd < r ? xcd * (q + 1) : r * (q + 1) + (xcd - r) * q) + idx;
}

// ---------------- fast path ws layout (bytes) ----------------
static const size_t WB_EB  = 0;          // fp8 E padded to NT rows (2,457,600; region reserves 4,915,200)
static const size_t WB_SIM = 4915200;    // bf16 sim tiles 1275 x 4096 (10,444,800)
static const size_t WB_N2  = 15360000;   // float[3200]
static const size_t WB_ARG = 15372800;   // u32[3200] packed (score20 | j12)
static const size_t WB_P1  = 15385600;   // float[2048] logexp partials (use 512)
static const size_t WB_P2  = 15393792;   // float[2048] scatter partials
static const size_t WB_GSL = 15401984;   // u32 [2048][64]
static const size_t WB_LSL = 15926272;   // f32 [2048][64]
static const size_t WB_CNT = 16450560;   // u32 [2048]
static const size_t WS_NEEDED = 16458752;

// ---------------- kernel A: zero + E->fp8(e4m3) ----------------
__global__ __launch_bounds__(256) void k_prep2(const float* __restrict__ E,
                                               unsigned char* __restrict__ Ef8,
                                               unsigned* __restrict__ zwords) {
    const int gid = blockIdx.x * 256 + threadIdx.x;
    const int gstride = gridDim.x * 256;

    for (int i = gid; i < 6400; i += gstride) zwords[i] = 0u;

    const int nchunks = NT * DN / 16;             // 153600 (16 elems/chunk)
    for (int chunk = gid; chunk < nchunks; chunk += gstride) {
        int row = chunk / (DN / 16);
        int cc = (chunk % (DN / 16)) * 16;
        unsigned char o[16];
        if (row < VN) {
            const float* src = E + (size_t)row * DN + cc;
#pragma unroll
            for (int q = 0; q < 4; ++q) {
                float4 v = *(const float4*)(src + q * 4);
                __hip_fp8_e4m3 a(v.x), b(v.y), c(v.z), d(v.w);
                o[q * 4 + 0] = a.__x;
                o[q * 4 + 1] = b.__x;
                o[q * 4 + 2] = c.__x;
                o[q * 4 + 3] = d.__x;
            }
        } else {
#pragma unroll
            for (int t = 0; t < 16; ++t) o[t] = 0;
        }
        *(uint4*)(Ef8 + (size_t)chunk * 16) = *(const uint4*)o;
    }
}

// ---------------- single Gram pass, fp8 staging (alone; L2 undisturbed) ----------------
// 1275 blocks, 4 waves each owning a 32x32 quadrant of a 64x64 tile.
__global__ __launch_bounds__(256) void k_gram64f(const unsigned char* __restrict__ Ef8,
                                                 float* __restrict__ n2,
                                                 unsigned short* __restrict__ simT) {
    __shared__ __align__(16) unsigned char As[64 * 64];   // 4KB
    __shared__ __align__(16) unsigned char Bs[64 * 64];
    const int tid = threadIdx.x;
    const int lane = tid & 63;
    const int w = tid >> 6;
    const int wr = w >> 1, wc = w & 1;

    int t = xcd_swz(blockIdx.x), bi = 0, rem = t;
    while (rem >= NB64 - bi) { rem -= NB64 - bi; ++bi; }
    const int bj = bi + rem;
    const int i0 = bi * 64, j0 = bj * 64;

    // staging: 4 chunks of 1024B per matrix per K-step; wave w owns chunk w.
    // chunk w covers rows w*16 .. w*16+15 (64B each). lane l -> row w*16 + (l>>2),
    // dest granule (16B) = l&3; source granule pre-swizzled: (l&3) ^ (row&3).
    const int srow = lane >> 2;                       // 0..15
    const int sgr = (lane & 3) ^ (srow & 3);          // swizzled source granule
    const int scol = sgr * 16;

    f32x4 acc[2][2] = {};

    for (int k0 = 0; k0 < DN; k0 += 64) {
        {
            int row = w * 16 + srow;
            gload16(Ef8 + (size_t)(i0 + row) * DN + k0 + scol, As + w * 1024 + lane * 16);
            gload16(Ef8 + (size_t)(j0 + row) * DN + k0 + scol, Bs + w * 1024 + lane * 16);
        }
        __syncthreads();
        const int rA = wr * 32 + (lane & 15);
        const int rB = wc * 32 + (lane & 15);
        const int kk = (lane >> 4) * 8;               // 0,8,16,24
#pragma unroll
        for (int ks = 0; ks < 2; ++ks) {
            const int cbyte = ks * 32 + kk;           // logical byte col in [0,64)
            const int goff = cbyte & 15;              // 0 or 8
            const int glog = cbyte >> 4;              // logical granule 0..3
            long a[2], b[2];
#pragma unroll
            for (int m = 0; m < 2; ++m) {
                int r = rA + m * 16;
                int g = glog ^ (r & 3);
                a[m] = *(const long*)(As + r * 64 + g * 16 + goff);
            }
#pragma unroll
            for (int n = 0; n < 2; ++n) {
                int r = rB + n * 16;
                int g = glog ^ (r & 3);
                b[n] = *(const long*)(Bs + r * 64 + g * 16 + goff);
            }
#pragma unroll
            for (int m = 0; m < 2; ++m)
#pragma unroll
                for (int n = 0; n < 2; ++n)
                    acc[m][n] = __builtin_amdgcn_mfma_f32_16x16x32_fp8_fp8(
                        a[m], b[n], acc[m][n], 0, 0, 0);
        }
        __syncthreads();
    }

    // C/D layout: col = lane&15, row = (lane>>4)*4 + reg  (dtype-independent)
    const int rr4 = (lane >> 4) * 4;

    // ---- sim tile store, lane-packed bf16: simT[t][tid][16] ----
    {
        unsigned op[8];
#pragma unroll
        for (int m = 0; m < 2; ++m)
#pragma unroll
            for (int n = 0; n < 2; ++n)
#pragma unroll
                for (int ih = 0; ih < 2; ++ih) {
                    unsigned lo = __float_as_uint(acc[m][n][ih * 2]);
                    lo += 0x7FFFu + ((lo >> 16) & 1u);
                    unsigned hi = __float_as_uint(acc[m][n][ih * 2 + 1]);
                    hi += 0x7FFFu + ((hi >> 16) & 1u);
                    op[(m * 2 + n) * 2 + ih] = (lo >> 16) | (hi & 0xFFFF0000u);
                }
        uint4* dst = (uint4*)(simT + (size_t)t * 4096 + (size_t)tid * 16);
        dst[0] = *(uint4*)&op[0];
        dst[1] = *(uint4*)&op[4];
    }

    // ---- n2 row sums ----
    __shared__ float red[64];
    if (tid < 64) red[tid] = 0.f;
    __syncthreads();
#pragma unroll
    for (int m = 0; m < 2; ++m)
#pragma unroll
        for (int i = 0; i < 4; ++i) {
            float s = acc[m][0][i] * acc[m][0][i] + acc[m][1][i] * acc[m][1][i];
            s += __shfl_xor(s, 1); s += __shfl_xor(s, 2);
            s += __shfl_xor(s, 4); s += __shfl_xor(s, 8);
            if ((lane & 15) == 0)
                atomicAdd(&red[wr * 32 + m * 16 + rr4 + i], s);
        }
    __syncthreads();
    if (tid < 64) atomicAdd(&n2[i0 + tid], red[tid]);
    // ---- n2 col sums (off-diagonal only) ----
    if (bi != bj) {
        __syncthreads();
        if (tid < 64) red[tid] = 0.f;
        __syncthreads();
#pragma unroll
        for (int n = 0; n < 2; ++n) {
            float s = 0.f;
#pragma unroll
            for (int m = 0; m < 2; ++m)
#pragma unroll
                for (int i = 0; i < 4; ++i) { float x = acc[m][n][i]; s += x * x; }
            s += __shfl_xor(s, 16); s += __shfl_xor(s, 32);
            if (lane < 16)
                atomicAdd(&red[wc * 32 + n * 16 + lane], s);
        }
        __syncthreads();
        if (tid < 64) atomicAdd(&n2[j0 + tid], red[tid]);
    }
}

// ---------------- mega2: amax | logexp | label-compaction by block role ----------------
__global__ __launch_bounds__(256) void k_mega2(const unsigned short* __restrict__ simT,
                                               const float* __restrict__ pred,
                                               const float* __restrict__ label,
                                               const float* __restrict__ n2,
                                               unsigned* __restrict__ argbest,
                                               float* __restrict__ part1,
                                               unsigned* __restrict__ gsl,
                                               float* __restrict__ lsl,
                                               unsigned* __restrict__ cntarr) {
    const int bid = blockIdx.x;
    const int tid = threadIdx.x;
    const int lane = tid & 63;
    const int w = tid >> 6;

    if (bid < NTRI64) {
        // ================= role A: argmax over stored sim tiles =================
        const int wr = w >> 1, wc = w & 1;
        int t = xcd_swz(bid), bi = 0, rem = t;
        while (rem >= NB64 - bi) { rem -= NB64 - bi; ++bi; }
        const int bj = bi + rem;
        const int i0 = bi * 64, j0 = bj * 64;

        __shared__ float rni_s[64], rnj_s[64];
        __shared__ unsigned rbest[64], cbest[64];
        if (tid < 64) {
            rni_s[tid] = rsqrtf(n2[i0 + tid]);
            rnj_s[tid] = rsqrtf(n2[j0 + tid]);
            rbest[tid] = 0u; cbest[tid] = 0u;
        }
        __syncthreads();

        const uint4* src = (const uint4*)(simT + (size_t)t * 4096 + (size_t)tid * 16);
        uint4 iv0 = src[0], iv1 = src[1];
        unsigned ip[8];
        *(uint4*)&ip[0] = iv0; *(uint4*)&ip[4] = iv1;

        const int rr4 = (lane >> 4) * 4;
        int rg[8]; float rni8[8];
#pragma unroll
        for (int m = 0; m < 2; ++m)
#pragma unroll
            for (int i = 0; i < 4; ++i) {
                int rl = wr * 32 + m * 16 + rr4 + i;
                rg[m * 4 + i] = i0 + rl;
                rni8[m * 4 + i] = rni_s[rl];
            }
        int cg2[2]; float rnj2[2];
#pragma unroll
        for (int n = 0; n < 2; ++n) {
            int cl = wc * 32 + n * 16 + (lane & 15);
            cg2[n] = j0 + cl;
            rnj2[n] = rnj_s[cl];
        }

        // row side: targets i (bi-block), candidates j (bj-block)
#pragma unroll
        for (int m = 0; m < 2; ++m)
#pragma unroll
            for (int i = 0; i < 4; ++i) {
                int ig = rg[m * 4 + i];
                unsigned best = 0u;
#pragma unroll
                for (int n = 0; n < 2; ++n) {
                    int jg = cg2[n];
                    if (jg < VN && jg != ig) {
                        unsigned wv = ip[(m * 2 + n) * 2 + (i >> 1)];
                        float v = __uint_as_float((i & 1) ? (wv & 0xFFFF0000u) : (wv << 16));
                        unsigned key = (sortable_f32(v * rnj2[n]) & 0xFFFFF000u) | (unsigned)jg;
                        best = max(best, key);
                    }
                }
                best = max(best, __shfl_xor(best, 1));
                best = max(best, __shfl_xor(best, 2));
                best = max(best, __shfl_xor(best, 4));
                best = max(best, __shfl_xor(best, 8));
                if ((lane & 15) == 0)
                    atomicMax(&rbest[wr * 32 + m * 16 + rr4 + i], best);
            }

        // col side (symmetry)
        if (bi != bj) {
#pragma unroll
            for (int n = 0; n < 2; ++n) {
                unsigned best = 0u;
#pragma unroll
                for (int m = 0; m < 2; ++m)
#pragma unroll
                    for (int i = 0; i < 4; ++i) {
                        int ig = rg[m * 4 + i];
                        if (ig < VN) {
                            unsigned wv = ip[(m * 2 + n) * 2 + (i >> 1)];
                            float v = __uint_as_float((i & 1) ? (wv & 0xFFFF0000u) : (wv << 16));
                            unsigned key = (sortable_f32(v * rni8[m * 4 + i]) & 0xFFFFF000u)
                                           | (unsigned)ig;
                            best = max(best, key);
                        }
                    }
                best = max(best, __shfl_xor(best, 16));
                best = max(best, __shfl_xor(best, 32));
                if (lane < 16)
                    atomicMax(&cbest[wc * 32 + n * 16 + lane], best);
            }
        }
        __syncthreads();
        if (tid < 64) {
            unsigned rb = rbest[tid];
            if (rb) atomicMax(&argbest[i0 + tid], rb);
            if (bi != bj) {
                unsigned cb = cbest[tid];
                if (cb) atomicMax(&argbest[j0 + tid], cb);
            }
        }
    } else if (bid < NTRI64 + NBLK_LOGEXP) {
        // ================= role B: pred logexp stream =================
        const int rb = bid - NTRI64;             // 0..511
        const float4* p4 = (const float4*)pred;
        const int n4 = BN * VN / 4;              // 1,602,048
        float acc = 0.f;
        for (int i = rb * 256 + tid; i < n4; i += NBLK_LOGEXP * 256) {
            float4 v = p4[i];
            acc += fmaxf(v.x, 0.f) + __logf(1.f + __expf(-fabsf(v.x)));
            acc += fmaxf(v.y, 0.f) + __logf(1.f + __expf(-fabsf(v.y)));
            acc += fmaxf(v.z, 0.f) + __logf(1.f + __expf(-fabsf(v.z)));
            acc += fmaxf(v.w, 0.f) + __logf(1.f + __expf(-fabsf(v.w)));
        }
        for (int off = 32; off; off >>= 1) acc += __shfl_down(acc, off);
        __shared__ float wsum[4];
        if (lane == 0) wsum[w] = acc;
        __syncthreads();
        if (tid == 0) part1[rb] = wsum[0] + wsum[1] + wsum[2] + wsum[3];
    } else {
        // ================= role C: label compaction, one wave per row =================
        const int row = (bid - NTRI64 - NBLK_LOGEXP) * 4 + w;   // 0..2047
        if (row < BN) {
            const float* lrow = label + (size_t)row * VN;
            float4 buf[12];
#pragma unroll
            for (int c = 0; c < 12; ++c)
                buf[c] = *(const float4*)(lrow + c * 256 + lane * 4);
            float tailv = 0.f;
            const int gtail = 3072 + lane;
            if (lane < VN - 3072) tailv = lrow[gtail];

            int base = 0;
#pragma unroll
            for (int c = 0; c < 12; ++c) {
                const float* f = (const float*)&buf[c];
#pragma unroll
                for (int e = 0; e < 4; ++e) {
                    float l = f[e];
                    unsigned long long mask = __ballot(l != 0.f);
                    if (l != 0.f) {
                        int pos = base + __popcll(mask & ((1ull << lane) - 1ull));
                        if (pos < 64) {
                            gsl[row * 64 + pos] = (unsigned)(c * 256 + lane * 4 + e);
                            lsl[row * 64 + pos] = l;
                        }
                    }
                    base += __popcll(mask);
                }
            }
            {
                unsigned long long mask = __ballot(tailv != 0.f);
                if (tailv != 0.f) {
                    int pos = base + __popcll(mask & ((1ull << lane) - 1ull));
                    if (pos < 64) {
                        gsl[row * 64 + pos] = (unsigned)gtail;
                        lsl[row * 64 + pos] = tailv;
                    }
                }
                base += __popcll(mask);
            }
            if (lane == 0) cntarr[row] = (unsigned)base;
        }
    }
}

// ---------------- scatter from compacted lists (one wave per row) ----------------
__global__ __launch_bounds__(64) void k_scatter(const float* __restrict__ pred,
                                                const float* __restrict__ label,
                                                const unsigned* __restrict__ argbest,
                                                const unsigned* __restrict__ gsl,
                                                const float* __restrict__ lsl,
                                                const unsigned* __restrict__ cntarr,
                                                float* __restrict__ part2) {
    const int i = blockIdx.x;
    const int lane = threadIdx.x;
    const int cnt = (int)cntarr[i];
    float contrib = 0.f;

    if (cnt <= 64) {
        unsigned g = 0, tgt = 0xFFFFFFFFu;
        float l = 0.f;
        if (lane < cnt) {
            g = gsl[i * 64 + lane];
            l = lsl[i * 64 + lane];
            tgt = argbest[g] & 0xFFFu;
        }
        __shared__ unsigned tg_s[64], g_s[64];
        tg_s[lane] = tgt; g_s[lane] = g;
        __syncthreads();
        if (lane < cnt) {
            bool keep = true;
            for (int o = 0; o < cnt; ++o)
                if (tg_s[o] == tgt && g_s[o] > g) { keep = false; break; }
            if (keep) contrib = pred[(size_t)i * VN + tgt] * l;
        }
    } else {
        // exact fallback: rescan raw label row
        __shared__ int c2;
        __shared__ unsigned short gs2[256], ts2[256];
        __shared__ float ls2[256];
        if (lane == 0) c2 = 0;
        __syncthreads();
        const float* lrow = label + (size_t)i * VN;
        for (int g = lane; g < VN; g += 64) {
            float l = lrow[g];
            if (l != 0.f) {
                int p = atomicAdd(&c2, 1);
                if (p < 256) {
                    gs2[p] = (unsigned short)g;
                    ls2[p] = l;
                    ts2[p] = (unsigned short)(argbest[g] & 0xFFFu);
                }
            }
        }
        __syncthreads();
        int m = min(c2, 256);
        for (int e = lane; e < m; e += 64) {
            bool keep = true;
            for (int o = 0; o < m; ++o)
                if (ts2[o] == ts2[e] && gs2[o] > gs2[e]) keep = false;
            if (keep) contrib += pred[(size_t)i * VN + ts2[e]] * ls2[e];
        }
    }

    for (int off = 32; off; off >>= 1) contrib += __shfl_down(contrib, off);
    if (lane == 0) part2[i] = contrib;
}

__global__ __launch_bounds__(256) void k_final(const float* __restrict__ part1, int p1n,
                                               const float* __restrict__ part2,
                                               float* __restrict__ out) {
    int tid = threadIdx.x;
    double acc = 0.0;
    for (int i = tid; i < p1n; i += 256) acc += (double)part1[i];
    for (int i = tid; i < BN; i += 256) acc -= (double)part2[i];
    __shared__ double red[256];
    red[tid] = acc;
    __syncthreads();
    for (int s = 128; s; s >>= 1) {
        if (tid < s) red[tid] += red[tid + s];
        __syncthreads();
    }
    if (tid == 0) out[0] = (float)(red[0] / (double)BN);
}

// ---------------- fallback path (small ws): fp32 Gram + scan scatter ----------------
__global__ __launch_bounds__(256) void k_zero(unsigned int* p, int nwords) {
    int idx = blockIdx.x * 256 + threadIdx.x;
    for (int i = idx; i < nwords; i += gridDim.x * 256) p[i] = 0u;
}

__global__ __launch_bounds__(256) void k_logexp(const float* __restrict__ pred,
                                                float* __restrict__ part1) {
    int tid = threadIdx.x;
    const float4* p4 = (const float4*)pred;
    const int n4 = BN * VN / 4;
    float acc = 0.f;
    for (int i = blockIdx.x * 256 + tid; i < n4; i += gridDim.x * 256) {
        float4 v = p4[i];
        acc += fmaxf(v.x, 0.f) + log1pf(__expf(-fabsf(v.x)));
        acc += fmaxf(v.y, 0.f) + log1pf(__expf(-fabsf(v.y)));
        acc += fmaxf(v.z, 0.f) + log1pf(__expf(-fabsf(v.z)));
        acc += fmaxf(v.w, 0.f) + log1pf(__expf(-fabsf(v.w)));
    }
    for (int off = 32; off; off >>= 1) acc += __shfl_down(acc, off);
    __shared__ float wsum[4];
    int lane = tid & 63, wid = tid >> 6;
    if (lane == 0) wsum[wid] = acc;
    __syncthreads();
    if (tid == 0) part1[blockIdx.x] = wsum[0] + wsum[1] + wsum[2] + wsum[3];
}

template <int PASS>
__global__ __launch_bounds__(256) void k_gemm(const float* __restrict__ E,
                                              float* __restrict__ n2,
                                              unsigned* __restrict__ argbest) {
    __shared__ float As[16][132];
    __shared__ float Bs[16][132];
    const int tid = threadIdx.x;
    const int tx = tid & 15, ty = tid >> 4;
    const int i0 = blockIdx.y * 128, j0 = blockIdx.x * 128;
    float acc[8][8] = {};

    for (int k0 = 0; k0 < DN; k0 += 16) {
#pragma unroll
        for (int h = 0; h < 2; ++h) {
            int f = tid + h * 256;
            int r = f >> 2;
            int kq = (f & 3) << 2;
            int gi = i0 + r;
            float4 va = make_float4(0.f, 0.f, 0.f, 0.f);
            if (gi < VN) va = *(const float4*)(E + gi * DN + k0 + kq);
            As[kq + 0][r] = va.x; As[kq + 1][r] = va.y;
            As[kq + 2][r] = va.z; As[kq + 3][r] = va.w;
            int gj = j0 + r;
            float4 vb = make_float4(0.f, 0.f, 0.f, 0.f);
            if (gj < VN) vb = *(const float4*)(E + gj * DN + k0 + kq);
            Bs[kq + 0][r] = vb.x; Bs[kq + 1][r] = vb.y;
            Bs[kq + 2][r] = vb.z; Bs[kq + 3][r] = vb.w;
        }
        __syncthreads();
#pragma unroll
        for (int k = 0; k < 16; ++k) {
            float a[8], b[8];
            *(float4*)&a[0] = *(const float4*)&As[k][ty * 8];
            *(float4*)&a[4] = *(const float4*)&As[k][ty * 8 + 4];
            *(float4*)&b[0] = *(const float4*)&Bs[k][tx * 8];
            *(float4*)&b[4] = *(const float4*)&Bs[k][tx * 8 + 4];
#pragma unroll
            for (int m = 0; m < 8; ++m)
#pragma unroll
                for (int n = 0; n < 8; ++n)
                    acc[m][n] = fmaf(a[m], b[n], acc[m][n]);
        }
        __syncthreads();
    }

    if (PASS == 0) {
        __shared__ float nrow[128];
        if (tid < 128) nrow[tid] = 0.f;
        __syncthreads();
#pragma unroll
        for (int m = 0; m < 8; ++m) {
            float s = 0.f;
#pragma unroll
            for (int n = 0; n < 8; ++n) s += acc[m][n] * acc[m][n];
            atomicAdd(&nrow[ty * 8 + m], s);
        }
        __syncthreads();
        if (tid < 128 && i0 + tid < VN) atomicAdd(&n2[i0 + tid], nrow[tid]);
    } else {
        __shared__ unsigned brow[128];
        if (tid < 128) brow[tid] = 0u;
        __syncthreads();
        float rnj[8];
#pragma unroll
        for (int n = 0; n < 8; ++n) {
            int j = j0 + tx * 8 + n;
            rnj[n] = (j < VN) ? rsqrtf(n2[j]) : 0.f;
        }
#pragma unroll
        for (int m = 0; m < 8; ++m) {
            int i = i0 + ty * 8 + m;
            unsigned best = 0u;
#pragma unroll
            for (int n = 0; n < 8; ++n) {
                int j = j0 + tx * 8 + n;
                if (j < VN && j != i) {
                    unsigned key = (sortable_f32(acc[m][n] * rnj[n]) & 0xFFFFF000u) | (unsigned)j;
                    best = max(best, key);
                }
            }
            atomicMax(&brow[ty * 8 + m], best);
        }
        __syncthreads();
        if (tid < 128 && i0 + tid < VN) atomicMax(&argbest[i0 + tid], brow[tid]);
    }
}

__global__ __launch_bounds__(256) void k_scatter_scan(const float* __restrict__ pred,
                                                      const float* __restrict__ label,
                                                      const unsigned* __restrict__ argbest,
                                                      float* __restrict__ part2) {
    int i = blockIdx.x;
    int tid = threadIdx.x;
    __shared__ int cnt;
    __shared__ unsigned short gs[256];
    __shared__ unsigned short ts[256];
    __shared__ float ls[256];
    if (tid == 0) cnt = 0;
    __syncthreads();
    const float* lrow = label + (size_t)i * VN;
    for (int g = tid; g < VN; g += 256) {
        float l = lrow[g];
        if (l != 0.f) {
            int p = atomicAdd(&cnt, 1);
            if (p < 256) {
                gs[p] = (unsigned short)g;
                ls[p] = l;
                ts[p] = (unsigned short)(argbest[g] & 0xFFFu);
            }
        }
    }
    __syncthreads();
    int m = min(cnt, 256);
    float contrib = 0.f;
    for (int e = tid; e < m; e += 256) {
        bool keep = true;
        for (int o = 0; o < m; ++o)
            if (ts[o] == ts[e] && gs[o] > gs[e]) keep = false;
        if (keep) contrib += pred[(size_t)i * VN + ts[e]] * ls[e];
    }
    for (int off = 32; off; off >>= 1) contrib += __shfl_down(contrib, off);
    __shared__ float wsum[4];
    int lane = tid & 63, wid = tid >> 6;
    if (lane == 0) wsum[wid] = contrib;
    __syncthreads();
    if (tid == 0) part2[i] = wsum[0] + wsum[1] + wsum[2] + wsum[3];
}

extern "C" void kernel_launch(void* const* d_in, const int* in_sizes, int n_in,
                              void* d_out, int out_size, void* d_ws, size_t ws_size,
                              hipStream_t stream) {
    (void)in_sizes; (void)n_in; (void)out_size;
    const float* pred  = (const float*)d_in[0];
    const float* label = (const float*)d_in[1];
    const float* E     = (const float*)d_in[2];
    float* out = (float*)d_out;
    char* wsb = (char*)d_ws;

    if (ws_size >= WS_NEEDED) {
        unsigned char* Ef8   = (unsigned char*)(wsb + WB_EB);
        unsigned short* simT = (unsigned short*)(wsb + WB_SIM);
        float* n2    = (float*)(wsb + WB_N2);
        unsigned* argbest = (unsigned*)(wsb + WB_ARG);
        float* part1 = (float*)(wsb + WB_P1);
        float* part2 = (float*)(wsb + WB_P2);
        unsigned* gsl = (unsigned*)(wsb + WB_GSL);
        float* lsl   = (float*)(wsb + WB_LSL);
        unsigned* cntarr = (unsigned*)(wsb + WB_CNT);

        k_prep2<<<1024, 256, 0, stream>>>(E, Ef8, (unsigned*)n2);
        k_gram64f<<<NTRI64, 256, 0, stream>>>(Ef8, n2, simT);
        k_mega2<<<GRID_MEGA2, 256, 0, stream>>>(simT, pred, label, n2, argbest,
                                                part1, gsl, lsl, cntarr);
        k_scatter<<<BN, 64, 0, stream>>>(pred, label, argbest, gsl, lsl, cntarr, part2);
        k_final<<<1, 256, 0, stream>>>(part1, NBLK_LOGEXP, part2, out);
    } else {
        // minimal-ws fallback: fp32 Gram path
        float* ws = (float*)d_ws;
        float* n2    = ws;
        unsigned* argbest = (unsigned*)(ws + 3200);
        float* part1 = ws + 6400;
        float* part2 = ws + 8448;
        k_zero<<<10, 256, 0, stream>>>((unsigned int*)ws, 6400);
        k_logexp<<<2048, 256, 0, stream>>>(pred, part1);
        dim3 g((VN + 127) / 128, (VN + 127) / 128);
        k_gemm<0><<<g, 256, 0, stream>>>(E, n2, argbest);
        k_gemm<1><<<g, 256, 0, stream>>>(E, n2, argbest);
        k_scatter_scan<<<BN, 256, 0, stream>>>(pred, label, argbest, part2);
        k_final<<<1, 256, 0, stream>>>(part1, 2048, part2, out);
    }
}

// Round 16
// 50.657 us; speedup vs baseline: 1.0988x; 1.0676x over previous
//
#include <hip/hip_runtime.h>
#include <hip/hip_bf16.h>

#define VN 3129
#define DN 768
#define BN 2048
#define NT 3200              // VN padded (multiple of 64 and 128)
#define NB64 50              // 64-wide tile blocks per side
#define NTRI64 1275          // 50*51/2
#define NBLK_LOGEXP 512
#define NBLK_COMPACT 512
#define GRID_MEGA2 (NTRI64 + NBLK_LOGEXP + NBLK_COMPACT)   // 2299

typedef __attribute__((ext_vector_type(8))) short bf16x8;
typedef __attribute__((ext_vector_type(4))) float f32x4;

typedef __attribute__((address_space(3))) void as3_void;
typedef __attribute__((address_space(1))) const void as1_cvoid;

__device__ __forceinline__ void gload16(const void* g, void* l) {
    __builtin_amdgcn_global_load_lds((as1_cvoid*)g, (as3_void*)l, 16, 0, 0);
}

__device__ __forceinline__ unsigned sortable_f32(float f) {
    unsigned u = __float_as_uint(f);
    return (u & 0x80000000u) ? ~u : (u | 0x80000000u);
}

// bijective XCD swizzle over the gram/amax range 0..1274 (m204 formula)
__device__ __forceinline__ int xcd_swz(int orig) {
    const int q = NTRI64 / 8, r = NTRI64 % 8;   // 159, 3
    int xcd = orig & 7, idx = orig >> 3;
    return (xcd < r ? xcd * (q + 1) : r * (q + 1) + (xcd - r) * q) + idx;
}

// ---------------- fast path ws layout (bytes) ----------------
static const size_t WB_EB  = 0;          // bf16 E padded to NT rows (4,915,200)
static const size_t WB_SIM = 4915200;    // bf16 sim tiles 1275 x 4096 (10,444,800)
static const size_t WB_N2  = 15360000;   // float[3200]
static const size_t WB_ARG = 15372800;   // u32[3200] packed (score20 | j12)
static const size_t WB_P1  = 15385600;   // float[2048] logexp partials (use 512)
static const size_t WB_P2  = 15393792;   // float[2048] scatter partials
static const size_t WB_GSL = 15401984;   // u32 [2048][64]
static const size_t WB_LSL = 15926272;   // f32 [2048][64]
static const size_t WB_CNT = 16450560;   // u32 [2048]
static const size_t WS_NEEDED = 16458752;

// ---------------- kernel A: zero + E->bf16 ----------------
__global__ __launch_bounds__(256) void k_prep2(const float* __restrict__ E,
                                               unsigned short* __restrict__ Eb,
                                               unsigned* __restrict__ zwords) {
    const int gid = blockIdx.x * 256 + threadIdx.x;
    const int gstride = gridDim.x * 256;

    for (int i = gid; i < 6400; i += gstride) zwords[i] = 0u;

    const int nchunks = NT * DN / 8;              // 307200
    for (int chunk = gid; chunk < nchunks; chunk += gstride) {
        int row = chunk / (DN / 8);
        int cc = (chunk % (DN / 8)) * 8;
        unsigned short o[8];
        if (row < VN) {
            const float* src = E + (size_t)row * DN + cc;
            float4 a = *(const float4*)src;
            float4 b = *(const float4*)(src + 4);
            float v[8] = {a.x, a.y, a.z, a.w, b.x, b.y, b.z, b.w};
#pragma unroll
            for (int t = 0; t < 8; ++t) {
                unsigned u = __float_as_uint(v[t]);
                u += 0x7FFFu + ((u >> 16) & 1u);      // RNE
                o[t] = (unsigned short)(u >> 16);
            }
        } else {
#pragma unroll
            for (int t = 0; t < 8; ++t) o[t] = 0;
        }
        *(uint4*)(Eb + (size_t)chunk * 8) = *(const uint4*)o;
    }
}

// ---------------- single Gram pass (alone; L2 undisturbed) ----------------
// 1275 blocks, 4 waves each owning a 32x32 quadrant of a 64x64 tile.
__global__ __launch_bounds__(256) void k_gram64s(const unsigned short* __restrict__ Eb,
                                                 float* __restrict__ n2,
                                                 unsigned short* __restrict__ simT) {
    __shared__ __align__(16) unsigned short As[64 * 64];
    __shared__ __align__(16) unsigned short Bs[64 * 64];
    const int tid = threadIdx.x;
    const int lane = tid & 63;
    const int w = tid >> 6;
    const int wr = w >> 1, wc = w & 1;

    int t = xcd_swz(blockIdx.x), bi = 0, rem = t;
    while (rem >= NB64 - bi) { rem -= NB64 - bi; ++bi; }
    const int bj = bi + rem;
    const int i0 = bi * 64, j0 = bj * 64;

    const int srow = lane >> 3;
    const int scol = 8 * ((lane & 7) ^ (lane >> 3));   // inverse-swizzled source col

    f32x4 acc[2][2] = {};

    for (int k0 = 0; k0 < DN; k0 += 64) {
#pragma unroll
        for (int q = 0; q < 2; ++q) {
            int ci = w * 2 + q;
            int row = ci * 8 + srow;
            gload16(Eb + (size_t)(i0 + row) * DN + k0 + scol, As + ci * 512);
            gload16(Eb + (size_t)(j0 + row) * DN + k0 + scol, Bs + ci * 512);
        }
        __syncthreads();
        const int rA = wr * 32 + (lane & 15);
        const int rB = wc * 32 + (lane & 15);
        const int swr = (lane & 7) << 4;
        const int kb = (lane >> 4) * 16;
#pragma unroll
        for (int ks = 0; ks < 2; ++ks) {
            const int cb = (kb + ks * 64) ^ swr;
            bf16x8 af[2], bfr[2];
#pragma unroll
            for (int m = 0; m < 2; ++m)
                af[m] = *(const bf16x8*)((const char*)As + (rA + m * 16) * 128 + cb);
#pragma unroll
            for (int n = 0; n < 2; ++n)
                bfr[n] = *(const bf16x8*)((const char*)Bs + (rB + n * 16) * 128 + cb);
#pragma unroll
            for (int m = 0; m < 2; ++m)
#pragma unroll
                for (int n = 0; n < 2; ++n)
                    acc[m][n] = __builtin_amdgcn_mfma_f32_16x16x32_bf16(
                        af[m], bfr[n], acc[m][n], 0, 0, 0);
        }
        __syncthreads();
    }

    // C/D layout: col = lane&15, row = (lane>>4)*4 + reg
    const int rr4 = (lane >> 4) * 4;

    // ---- sim tile store, lane-packed bf16: simT[t][tid][16] ----
    {
        unsigned op[8];
#pragma unroll
        for (int m = 0; m < 2; ++m)
#pragma unroll
            for (int n = 0; n < 2; ++n)
#pragma unroll
                for (int ih = 0; ih < 2; ++ih) {
                    unsigned lo = __float_as_uint(acc[m][n][ih * 2]);
                    lo += 0x7FFFu + ((lo >> 16) & 1u);
                    unsigned hi = __float_as_uint(acc[m][n][ih * 2 + 1]);
                    hi += 0x7FFFu + ((hi >> 16) & 1u);
                    op[(m * 2 + n) * 2 + ih] = (lo >> 16) | (hi & 0xFFFF0000u);
                }
        uint4* dst = (uint4*)(simT + (size_t)t * 4096 + (size_t)tid * 16);
        dst[0] = *(uint4*)&op[0];
        dst[1] = *(uint4*)&op[4];
    }

    // ---- n2 row sums ----
    __shared__ float red[64];
    if (tid < 64) red[tid] = 0.f;
    __syncthreads();
#pragma unroll
    for (int m = 0; m < 2; ++m)
#pragma unroll
        for (int i = 0; i < 4; ++i) {
            float s = acc[m][0][i] * acc[m][0][i] + acc[m][1][i] * acc[m][1][i];
            s += __shfl_xor(s, 1); s += __shfl_xor(s, 2);
            s += __shfl_xor(s, 4); s += __shfl_xor(s, 8);
            if ((lane & 15) == 0)
                atomicAdd(&red[wr * 32 + m * 16 + rr4 + i], s);
        }
    __syncthreads();
    if (tid < 64) atomicAdd(&n2[i0 + tid], red[tid]);
    // ---- n2 col sums (off-diagonal only) ----
    if (bi != bj) {
        __syncthreads();
        if (tid < 64) red[tid] = 0.f;
        __syncthreads();
#pragma unroll
        for (int n = 0; n < 2; ++n) {
            float s = 0.f;
#pragma unroll
            for (int m = 0; m < 2; ++m)
#pragma unroll
                for (int i = 0; i < 4; ++i) { float x = acc[m][n][i]; s += x * x; }
            s += __shfl_xor(s, 16); s += __shfl_xor(s, 32);
            if (lane < 16)
                atomicAdd(&red[wc * 32 + n * 16 + lane], s);
        }
        __syncthreads();
        if (tid < 64) atomicAdd(&n2[j0 + tid], red[tid]);
    }
}

// ---------------- mega2: amax | logexp | label-compaction by block role ----------------
// amax streams simT once (no reuse) -> HBM streams can overlap without evicting
// anything the amax role depends on.
__global__ __launch_bounds__(256) void k_mega2(const unsigned short* __restrict__ simT,
                                               const float* __restrict__ pred,
                                               const float* __restrict__ label,
                                               const float* __restrict__ n2,
                                               unsigned* __restrict__ argbest,
                                               float* __restrict__ part1,
                                               unsigned* __restrict__ gsl,
                                               float* __restrict__ lsl,
                                               unsigned* __restrict__ cntarr) {
    const int bid = blockIdx.x;
    const int tid = threadIdx.x;
    const int lane = tid & 63;
    const int w = tid >> 6;

    if (bid < NTRI64) {
        // ================= role A: argmax over stored sim tiles =================
        const int wr = w >> 1, wc = w & 1;
        int t = xcd_swz(bid), bi = 0, rem = t;
        while (rem >= NB64 - bi) { rem -= NB64 - bi; ++bi; }
        const int bj = bi + rem;
        const int i0 = bi * 64, j0 = bj * 64;

        __shared__ float rni_s[64], rnj_s[64];
        __shared__ unsigned rbest[64], cbest[64];
        if (tid < 64) {
            rni_s[tid] = rsqrtf(n2[i0 + tid]);
            rnj_s[tid] = rsqrtf(n2[j0 + tid]);
            rbest[tid] = 0u; cbest[tid] = 0u;
        }
        __syncthreads();

        const uint4* src = (const uint4*)(simT + (size_t)t * 4096 + (size_t)tid * 16);
        uint4 iv0 = src[0], iv1 = src[1];
        unsigned ip[8];
        *(uint4*)&ip[0] = iv0; *(uint4*)&ip[4] = iv1;

        const int rr4 = (lane >> 4) * 4;
        int rg[8]; float rni8[8];
#pragma unroll
        for (int m = 0; m < 2; ++m)
#pragma unroll
            for (int i = 0; i < 4; ++i) {
                int rl = wr * 32 + m * 16 + rr4 + i;
                rg[m * 4 + i] = i0 + rl;
                rni8[m * 4 + i] = rni_s[rl];
            }
        int cg2[2]; float rnj2[2];
#pragma unroll
        for (int n = 0; n < 2; ++n) {
            int cl = wc * 32 + n * 16 + (lane & 15);
            cg2[n] = j0 + cl;
            rnj2[n] = rnj_s[cl];
        }

        // row side: targets i (bi-block), candidates j (bj-block)
#pragma unroll
        for (int m = 0; m < 2; ++m)
#pragma unroll
            for (int i = 0; i < 4; ++i) {
                int ig = rg[m * 4 + i];
                unsigned best = 0u;
#pragma unroll
                for (int n = 0; n < 2; ++n) {
                    int jg = cg2[n];
                    if (jg < VN && jg != ig) {
                        unsigned wv = ip[(m * 2 + n) * 2 + (i >> 1)];
                        float v = __uint_as_float((i & 1) ? (wv & 0xFFFF0000u) : (wv << 16));
                        unsigned key = (sortable_f32(v * rnj2[n]) & 0xFFFFF000u) | (unsigned)jg;
                        best = max(best, key);
                    }
                }
                best = max(best, __shfl_xor(best, 1));
                best = max(best, __shfl_xor(best, 2));
                best = max(best, __shfl_xor(best, 4));
                best = max(best, __shfl_xor(best, 8));
                if ((lane & 15) == 0)
                    atomicMax(&rbest[wr * 32 + m * 16 + rr4 + i], best);
            }

        // col side (symmetry)
        if (bi != bj) {
#pragma unroll
            for (int n = 0; n < 2; ++n) {
                unsigned best = 0u;
#pragma unroll
                for (int m = 0; m < 2; ++m)
#pragma unroll
                    for (int i = 0; i < 4; ++i) {
                        int ig = rg[m * 4 + i];
                        if (ig < VN) {
                            unsigned wv = ip[(m * 2 + n) * 2 + (i >> 1)];
                            float v = __uint_as_float((i & 1) ? (wv & 0xFFFF0000u) : (wv << 16));
                            unsigned key = (sortable_f32(v * rni8[m * 4 + i]) & 0xFFFFF000u)
                                           | (unsigned)ig;
                            best = max(best, key);
                        }
                    }
                best = max(best, __shfl_xor(best, 16));
                best = max(best, __shfl_xor(best, 32));
                if (lane < 16)
                    atomicMax(&cbest[wc * 32 + n * 16 + lane], best);
            }
        }
        __syncthreads();
        if (tid < 64) {
            unsigned rb = rbest[tid];
            if (rb) atomicMax(&argbest[i0 + tid], rb);
            if (bi != bj) {
                unsigned cb = cbest[tid];
                if (cb) atomicMax(&argbest[j0 + tid], cb);
            }
        }
    } else if (bid < NTRI64 + NBLK_LOGEXP) {
        // ================= role B: pred logexp stream =================
        const int rb = bid - NTRI64;             // 0..511
        const float4* p4 = (const float4*)pred;
        const int n4 = BN * VN / 4;              // 1,602,048
        float acc = 0.f;
        for (int i = rb * 256 + tid; i < n4; i += NBLK_LOGEXP * 256) {
            float4 v = p4[i];
            acc += fmaxf(v.x, 0.f) + __logf(1.f + __expf(-fabsf(v.x)));
            acc += fmaxf(v.y, 0.f) + __logf(1.f + __expf(-fabsf(v.y)));
            acc += fmaxf(v.z, 0.f) + __logf(1.f + __expf(-fabsf(v.z)));
            acc += fmaxf(v.w, 0.f) + __logf(1.f + __expf(-fabsf(v.w)));
        }
        for (int off = 32; off; off >>= 1) acc += __shfl_down(acc, off);
        __shared__ float wsum[4];
        if (lane == 0) wsum[w] = acc;
        __syncthreads();
        if (tid == 0) part1[rb] = wsum[0] + wsum[1] + wsum[2] + wsum[3];
    } else {
        // ================= role C: label compaction, one wave per row =================
        const int row = (bid - NTRI64 - NBLK_LOGEXP) * 4 + w;   // 0..2047
        if (row < BN) {
            const float* lrow = label + (size_t)row * VN;
            float4 buf[12];
#pragma unroll
            for (int c = 0; c < 12; ++c)
                buf[c] = *(const float4*)(lrow + c * 256 + lane * 4);
            float tailv = 0.f;
            const int gtail = 3072 + lane;
            if (lane < VN - 3072) tailv = lrow[gtail];

            int base = 0;
#pragma unroll
            for (int c = 0; c < 12; ++c) {
                const float* f = (const float*)&buf[c];
#pragma unroll
                for (int e = 0; e < 4; ++e) {
                    float l = f[e];
                    unsigned long long mask = __ballot(l != 0.f);
                    if (l != 0.f) {
                        int pos = base + __popcll(mask & ((1ull << lane) - 1ull));
                        if (pos < 64) {
                            gsl[row * 64 + pos] = (unsigned)(c * 256 + lane * 4 + e);
                            lsl[row * 64 + pos] = l;
                        }
                    }
                    base += __popcll(mask);
                }
            }
            {
                unsigned long long mask = __ballot(tailv != 0.f);
                if (tailv != 0.f) {
                    int pos = base + __popcll(mask & ((1ull << lane) - 1ull));
                    if (pos < 64) {
                        gsl[row * 64 + pos] = (unsigned)gtail;
                        lsl[row * 64 + pos] = tailv;
                    }
                }
                base += __popcll(mask);
            }
            if (lane == 0) cntarr[row] = (unsigned)base;
        }
    }
}

// ---------------- scatter from compacted lists (one wave per row) ----------------
__global__ __launch_bounds__(64) void k_scatter(const float* __restrict__ pred,
                                                const float* __restrict__ label,
                                                const unsigned* __restrict__ argbest,
                                                const unsigned* __restrict__ gsl,
                                                const float* __restrict__ lsl,
                                                const unsigned* __restrict__ cntarr,
                                                float* __restrict__ part2) {
    const int i = blockIdx.x;
    const int lane = threadIdx.x;
    const int cnt = (int)cntarr[i];
    float contrib = 0.f;

    if (cnt <= 64) {
        unsigned g = 0, tgt = 0xFFFFFFFFu;
        float l = 0.f;
        if (lane < cnt) {
            g = gsl[i * 64 + lane];
            l = lsl[i * 64 + lane];
            tgt = argbest[g] & 0xFFFu;
        }
        __shared__ unsigned tg_s[64], g_s[64];
        tg_s[lane] = tgt; g_s[lane] = g;
        __syncthreads();
        if (lane < cnt) {
            bool keep = true;
            for (int o = 0; o < cnt; ++o)
                if (tg_s[o] == tgt && g_s[o] > g) { keep = false; break; }
            if (keep) contrib = pred[(size_t)i * VN + tgt] * l;
        }
    } else {
        // exact fallback: rescan raw label row
        __shared__ int c2;
        __shared__ unsigned short gs2[256], ts2[256];
        __shared__ float ls2[256];
        if (lane == 0) c2 = 0;
        __syncthreads();
        const float* lrow = label + (size_t)i * VN;
        for (int g = lane; g < VN; g += 64) {
            float l = lrow[g];
            if (l != 0.f) {
                int p = atomicAdd(&c2, 1);
                if (p < 256) {
                    gs2[p] = (unsigned short)g;
                    ls2[p] = l;
                    ts2[p] = (unsigned short)(argbest[g] & 0xFFFu);
                }
            }
        }
        __syncthreads();
        int m = min(c2, 256);
        for (int e = lane; e < m; e += 64) {
            bool keep = true;
            for (int o = 0; o < m; ++o)
                if (ts2[o] == ts2[e] && gs2[o] > gs2[e]) keep = false;
            if (keep) contrib += pred[(size_t)i * VN + ts2[e]] * ls2[e];
        }
    }

    for (int off = 32; off; off >>= 1) contrib += __shfl_down(contrib, off);
    if (lane == 0) part2[i] = contrib;
}

__global__ __launch_bounds__(256) void k_final(const float* __restrict__ part1, int p1n,
                                               const float* __restrict__ part2,
                                               float* __restrict__ out) {
    int tid = threadIdx.x;
    double acc = 0.0;
    for (int i = tid; i < p1n; i += 256) acc += (double)part1[i];
    for (int i = tid; i < BN; i += 256) acc -= (double)part2[i];
    __shared__ double red[256];
    red[tid] = acc;
    __syncthreads();
    for (int s = 128; s; s >>= 1) {
        if (tid < s) red[tid] += red[tid + s];
        __syncthreads();
    }
    if (tid == 0) out[0] = (float)(red[0] / (double)BN);
}

// ---------------- fallback path (small ws): fp32 Gram + scan scatter ----------------
__global__ __launch_bounds__(256) void k_zero(unsigned int* p, int nwords) {
    int idx = blockIdx.x * 256 + threadIdx.x;
    for (int i = idx; i < nwords; i += gridDim.x * 256) p[i] = 0u;
}

__global__ __launch_bounds__(256) void k_logexp(const float* __restrict__ pred,
                                                float* __restrict__ part1) {
    int tid = threadIdx.x;
    const float4* p4 = (const float4*)pred;
    const int n4 = BN * VN / 4;
    float acc = 0.f;
    for (int i = blockIdx.x * 256 + tid; i < n4; i += gridDim.x * 256) {
        float4 v = p4[i];
        acc += fmaxf(v.x, 0.f) + log1pf(__expf(-fabsf(v.x)));
        acc += fmaxf(v.y, 0.f) + log1pf(__expf(-fabsf(v.y)));
        acc += fmaxf(v.z, 0.f) + log1pf(__expf(-fabsf(v.z)));
        acc += fmaxf(v.w, 0.f) + log1pf(__expf(-fabsf(v.w)));
    }
    for (int off = 32; off; off >>= 1) acc += __shfl_down(acc, off);
    __shared__ float wsum[4];
    int lane = tid & 63, wid = tid >> 6;
    if (lane == 0) wsum[wid] = acc;
    __syncthreads();
    if (tid == 0) part1[blockIdx.x] = wsum[0] + wsum[1] + wsum[2] + wsum[3];
}

template <int PASS>
__global__ __launch_bounds__(256) void k_gemm(const float* __restrict__ E,
                                              float* __restrict__ n2,
                                              unsigned* __restrict__ argbest) {
    __shared__ float As[16][132];
    __shared__ float Bs[16][132];
    const int tid = threadIdx.x;
    const int tx = tid & 15, ty = tid >> 4;
    const int i0 = blockIdx.y * 128, j0 = blockIdx.x * 128;
    float acc[8][8] = {};

    for (int k0 = 0; k0 < DN; k0 += 16) {
#pragma unroll
        for (int h = 0; h < 2; ++h) {
            int f = tid + h * 256;
            int r = f >> 2;
            int kq = (f & 3) << 2;
            int gi = i0 + r;
            float4 va = make_float4(0.f, 0.f, 0.f, 0.f);
            if (gi < VN) va = *(const float4*)(E + gi * DN + k0 + kq);
            As[kq + 0][r] = va.x; As[kq + 1][r] = va.y;
            As[kq + 2][r] = va.z; As[kq + 3][r] = va.w;
            int gj = j0 + r;
            float4 vb = make_float4(0.f, 0.f, 0.f, 0.f);
            if (gj < VN) vb = *(const float4*)(E + gj * DN + k0 + kq);
            Bs[kq + 0][r] = vb.x; Bs[kq + 1][r] = vb.y;
            Bs[kq + 2][r] = vb.z; Bs[kq + 3][r] = vb.w;
        }
        __syncthreads();
#pragma unroll
        for (int k = 0; k < 16; ++k) {
            float a[8], b[8];
            *(float4*)&a[0] = *(const float4*)&As[k][ty * 8];
            *(float4*)&a[4] = *(const float4*)&As[k][ty * 8 + 4];
            *(float4*)&b[0] = *(const float4*)&Bs[k][tx * 8];
            *(float4*)&b[4] = *(const float4*)&Bs[k][tx * 8 + 4];
#pragma unroll
            for (int m = 0; m < 8; ++m)
#pragma unroll
                for (int n = 0; n < 8; ++n)
                    acc[m][n] = fmaf(a[m], b[n], acc[m][n]);
        }
        __syncthreads();
    }

    if (PASS == 0) {
        __shared__ float nrow[128];
        if (tid < 128) nrow[tid] = 0.f;
        __syncthreads();
#pragma unroll
        for (int m = 0; m < 8; ++m) {
            float s = 0.f;
#pragma unroll
            for (int n = 0; n < 8; ++n) s += acc[m][n] * acc[m][n];
            atomicAdd(&nrow[ty * 8 + m], s);
        }
        __syncthreads();
        if (tid < 128 && i0 + tid < VN) atomicAdd(&n2[i0 + tid], nrow[tid]);
    } else {
        __shared__ unsigned brow[128];
        if (tid < 128) brow[tid] = 0u;
        __syncthreads();
        float rnj[8];
#pragma unroll
        for (int n = 0; n < 8; ++n) {
            int j = j0 + tx * 8 + n;
            rnj[n] = (j < VN) ? rsqrtf(n2[j]) : 0.f;
        }
#pragma unroll
        for (int m = 0; m < 8; ++m) {
            int i = i0 + ty * 8 + m;
            unsigned best = 0u;
#pragma unroll
            for (int n = 0; n < 8; ++n) {
                int j = j0 + tx * 8 + n;
                if (j < VN && j != i) {
                    unsigned key = (sortable_f32(acc[m][n] * rnj[n]) & 0xFFFFF000u) | (unsigned)j;
                    best = max(best, key);
                }
            }
            atomicMax(&brow[ty * 8 + m], best);
        }
        __syncthreads();
        if (tid < 128 && i0 + tid < VN) atomicMax(&argbest[i0 + tid], brow[tid]);
    }
}

__global__ __launch_bounds__(256) void k_scatter_scan(const float* __restrict__ pred,
                                                      const float* __restrict__ label,
                                                      const unsigned* __restrict__ argbest,
                                                      float* __restrict__ part2) {
    int i = blockIdx.x;
    int tid = threadIdx.x;
    __shared__ int cnt;
    __shared__ unsigned short gs[256];
    __shared__ unsigned short ts[256];
    __shared__ float ls[256];
    if (tid == 0) cnt = 0;
    __syncthreads();
    const float* lrow = label + (size_t)i * VN;
    for (int g = tid; g < VN; g += 256) {
        float l = lrow[g];
        if (l != 0.f) {
            int p = atomicAdd(&cnt, 1);
            if (p < 256) {
                gs[p] = (unsigned short)g;
                ls[p] = l;
                ts[p] = (unsigned short)(argbest[g] & 0xFFFu);
            }
        }
    }
    __syncthreads();
    int m = min(cnt, 256);
    float contrib = 0.f;
    for (int e = tid; e < m; e += 256) {
        bool keep = true;
        for (int o = 0; o < m; ++o)
            if (ts[o] == ts[e] && gs[o] > gs[e]) keep = false;
        if (keep) contrib += pred[(size_t)i * VN + ts[e]] * ls[e];
    }
    for (int off = 32; off; off >>= 1) contrib += __shfl_down(contrib, off);
    __shared__ float wsum[4];
    int lane = tid & 63, wid = tid >> 6;
    if (lane == 0) wsum[wid] = contrib;
    __syncthreads();
    if (tid == 0) part2[i] = wsum[0] + wsum[1] + wsum[2] + wsum[3];
}

extern "C" void kernel_launch(void* const* d_in, const int* in_sizes, int n_in,
                              void* d_out, int out_size, void* d_ws, size_t ws_size,
                              hipStream_t stream) {
    (void)in_sizes; (void)n_in; (void)out_size;
    const float* pred  = (const float*)d_in[0];
    const float* label = (const float*)d_in[1];
    const float* E     = (const float*)d_in[2];
    float* out = (float*)d_out;
    char* wsb = (char*)d_ws;

    if (ws_size >= WS_NEEDED) {
        unsigned short* Eb   = (unsigned short*)(wsb + WB_EB);
        unsigned short* simT = (unsigned short*)(wsb + WB_SIM);
        float* n2    = (float*)(wsb + WB_N2);
        unsigned* argbest = (unsigned*)(wsb + WB_ARG);
        float* part1 = (float*)(wsb + WB_P1);
        float* part2 = (float*)(wsb + WB_P2);
        unsigned* gsl = (unsigned*)(wsb + WB_GSL);
        float* lsl   = (float*)(wsb + WB_LSL);
        unsigned* cntarr = (unsigned*)(wsb + WB_CNT);

        k_prep2<<<1024, 256, 0, stream>>>(E, Eb, (unsigned*)n2);
        k_gram64s<<<NTRI64, 256, 0, stream>>>(Eb, n2, simT);
        k_mega2<<<GRID_MEGA2, 256, 0, stream>>>(simT, pred, label, n2, argbest,
                                                part1, gsl, lsl, cntarr);
        k_scatter<<<BN, 64, 0, stream>>>(pred, label, argbest, gsl, lsl, cntarr, part2);
        k_final<<<1, 256, 0, stream>>>(part1, NBLK_LOGEXP, part2, out);
    } else {
        // minimal-ws fallback: fp32 Gram path
        float* ws = (float*)d_ws;
        float* n2    = ws;
        unsigned* argbest = (unsigned*)(ws + 3200);
        float* part1 = ws + 6400;
        float* part2 = ws + 8448;
        k_zero<<<10, 256, 0, stream>>>((unsigned int*)ws, 6400);
        k_logexp<<<2048, 256, 0, stream>>>(pred, part1);
        dim3 g((VN + 127) / 128, (VN + 127) / 128);
        k_gemm<0><<<g, 256, 0, stream>>>(E, n2, argbest);
        k_gemm<1><<<g, 256, 0, stream>>>(E, n2, argbest);
        k_scatter_scan<<<BN, 256, 0, stream>>>(pred, label, argbest, part2);
        k_final<<<1, 256, 0, stream>>>(part1, 2048, part2, out);
    }
}